// Round 4
// baseline (306.619 us; speedup 1.0000x reference)
//
#include <hip/hip_runtime.h>
#include <hip/hip_bf16.h>

// Problem constants
#define S     2048
#define D     1024
#define NH    8
#define NKV   2
#define HD    128
#define WS_   64
#define E_    16
#define HDIM  512
#define TOPK  2
#define NTOK  S
#define NSLOT (S*TOPK)         // 4096
#define QKV_M (D + 2*NKV*HD)   // 1536 fused q|k|v columns
#define KOFF  D                // 1024
#define VOFF  (D + NKV*HD)     // 1280
#define QB    8                // queries per attention block
#define WROWS (QB + WS_ - 1)   // 71 key rows per window
#define KPITCH 73              // KT key pitch (float4 units)
#define VPADF  132             // Vs row stride in floats

typedef __attribute__((ext_vector_type(8))) short bf16x8;
typedef __attribute__((ext_vector_type(4))) float floatx4;

__device__ inline short f2bf(float f) {
    __hip_bfloat16 b = __float2bfloat16(f);
    return *reinterpret_cast<short*>(&b);
}

// ---------------------------------------------------------------------------
// All weight prep + attention pre-norm in ONE launch:
//   6 transpose+convert regions + bias concat + router_w transpose
//   + zero-init of router-accumulators + rmsnorm(x)->bf16 region.
// ---------------------------------------------------------------------------
__global__ __launch_bounds__(256) void tconv_all(
    const float* __restrict__ wq, const float* __restrict__ wk,
    const float* __restrict__ wv, const float* __restrict__ wo,
    const float* __restrict__ w1, const float* __restrict__ w2,
    const float* __restrict__ bq, const float* __restrict__ bk,
    const float* __restrict__ bv, const float* __restrict__ router_w,
    short* __restrict__ wqkvT, short* __restrict__ woT,
    short* __restrict__ w1T, short* __restrict__ w2T,
    float* __restrict__ bqkv, float* __restrict__ rwT,
    const float* __restrict__ x, const float* __restrict__ norm1_w,
    short* __restrict__ h_bf, float* __restrict__ gcsum,
    int* __restrict__ ghist)
{
    int id = blockIdx.x;
    if (id >= 18983) {                       // 2048 rmsnorm blocks
        int row = id - 18983, t = threadIdx.x;
        float4 v = ((const float4*)(x + (size_t)row * D))[t];
        float ss = v.x*v.x + v.y*v.y + v.z*v.z + v.w*v.w;
        #pragma unroll
        for (int off = 32; off; off >>= 1) ss += __shfl_xor(ss, off, 64);
        __shared__ float red[4];
        if ((t & 63) == 0) red[t >> 6] = ss;
        __syncthreads();
        float total = red[0] + red[1] + red[2] + red[3];
        float scale = rsqrtf(total * (1.0f / (float)D) + 1e-6f);
        float4 wv4 = ((const float4*)norm1_w)[t];
        short4 ob;
        ob.x = f2bf(v.x * scale * wv4.x); ob.y = f2bf(v.y * scale * wv4.y);
        ob.z = f2bf(v.z * scale * wv4.z); ob.w = f2bf(v.w * scale * wv4.w);
        ((short4*)(h_bf + (size_t)row * D))[t] = ob;
        return;
    }
    if (id == 18982) {                       // zero router accumulators
        int t = threadIdx.x;
        if (t < E_) gcsum[t] = 0.f;
        else if (t < 2 * E_) ghist[t - E_] = 0;
        return;
    }
    if (id >= 18950) {                       // 32 router_w transpose blocks
        int ky = id - 18950;                 // 0..31
        int t = threadIdx.x;
        int r = t >> 4, c = t & 15;
        int k0 = ky * 32;
        rwT[c * D + k0 + r]      = router_w[(k0 + r) * E_ + c];
        rwT[c * D + k0 + r + 16] = router_w[(k0 + r + 16) * E_ + c];
        return;
    }
    if (id >= 18944) {                       // 6 bias-concat blocks
        int t = (id - 18944) * 256 + threadIdx.x;
        if (t < D) bqkv[t] = bq[t];
        else if (t < VOFF) bqkv[t] = bk[t - D];
        else bqkv[t] = bv[t - VOFF];
        return;
    }
    const float* in; short* outp; int K, M, mx, ky;
    if (id < 1024)      { in = wq; outp = wqkvT;                  K = D; M = D;   int l = id;        mx = l & 31; ky = l >> 5; }
    else if (id < 1280) { in = wk; outp = wqkvT + (size_t)KOFF*D; K = D; M = 256; int l = id - 1024; mx = l & 7;  ky = l >> 3; }
    else if (id < 1536) { in = wv; outp = wqkvT + (size_t)VOFF*D; K = D; M = 256; int l = id - 1280; mx = l & 7;  ky = l >> 3; }
    else if (id < 2560) { in = wo; outp = woT;                    K = D; M = D;   int l = id - 1536; mx = l & 31; ky = l >> 5; }
    else if (id < 10752){ int l = id - 2560;  int e = l >> 9; int r = l & 511;
                          in = w1 + (size_t)e * D * HDIM; outp = w1T + (size_t)e * D * HDIM;
                          K = D; M = HDIM; mx = r & 15; ky = r >> 4; }
    else                { int l = id - 10752; int e = l >> 9; int r = l & 511;
                          in = w2 + (size_t)e * D * HDIM; outp = w2T + (size_t)e * D * HDIM;
                          K = HDIM; M = D; mx = r & 31; ky = r >> 5; }
    __shared__ float tile[32][33];
    int t = threadIdx.x, r = t >> 3, c4 = (t & 7) * 4;
    int k0 = ky * 32, m0 = mx * 32;
    float4 v = *(const float4*)&in[(size_t)(k0 + r) * M + m0 + c4];
    tile[r][c4 + 0] = v.x; tile[r][c4 + 1] = v.y;
    tile[r][c4 + 2] = v.z; tile[r][c4 + 3] = v.w;
    __syncthreads();
    short4 o;
    o.x = f2bf(tile[c4 + 0][r]);
    o.y = f2bf(tile[c4 + 1][r]);
    o.z = f2bf(tile[c4 + 2][r]);
    o.w = f2bf(tile[c4 + 3][r]);
    *(short4*)&outp[(size_t)(m0 + r) * K + k0 + c4] = o;
}

// ---------------------------------------------------------------------------
// bf16 MFMA GEMM: 64x64 tile, BK=64, TRIPLE-buffered LDS (48 KB),
// global_load_lds width=16 staging issued TWO tiles ahead, raw s_barrier
// with COUNTED s_waitcnt vmcnt(4) (T4): the newest tile's 4 loads stay in
// flight across the barrier; full drain only at the last two iterations.
// Epilogue operands (bias/res/gate/map) prefetched into registers BEFORE
// the loop so no stray VMEM perturbs the vmcnt arithmetic.
// XOR involution swizzle on source+read (R1-proven). MFMA accumulation
// order per output element identical to the proven kernel -> numerics
// preserved.
// V=0: C fp32 (QKV)            V=1: +bias+res (WO->x1)
// V=2: MoE1 silu->bf16, A-rows indirect via tok_map (gather fused)
// V=3: MoE2 atomic-accumulate gate*(val+bias) into out[token] (combine fused)
// ---------------------------------------------------------------------------
#define BT   64
#define BKS  64                 // k shorts per step
#define BUFS (BT * BKS)         // 4096 shorts = 8 KB

__device__ inline void gld16(const short* g, short* l) {
    __builtin_amdgcn_global_load_lds(
        (const __attribute__((address_space(1))) unsigned int*)g,
        (__attribute__((address_space(3))) unsigned int*)l, 16, 0, 0);
}

template <int V>
__global__ __launch_bounds__(256) void mgemm(
    const short* __restrict__ A, const short* __restrict__ Bt,
    const float* __restrict__ bias, float* __restrict__ C,
    short* __restrict__ Cb, const float* __restrict__ res, int K, int M,
    const int* __restrict__ offs, const float* __restrict__ tok_gate,
    const int* __restrict__ tok_map)
{
    int e = (V >= 2) ? blockIdx.z : 0;
    const short* Bte = (V >= 2) ? Bt + (size_t)e * M * K : Bt;
    const float* be  = (V >= 2) ? bias + (size_t)e * M : bias;

    int row_lo, row_hi;
    if (V >= 2) {
        row_lo = offs[e] + blockIdx.y * BT;
        row_hi = offs[e + 1];
        if (row_lo >= row_hi) return;
    } else {
        row_lo = blockIdx.y * BT;
        row_hi = 1 << 30;
    }
    int col0 = blockIdx.x * BT;

    __shared__ __align__(16) short As[3 * BUFS];   // 24 KB
    __shared__ __align__(16) short Bs[3 * BUFS];   // 24 KB

    int t = threadIdx.x;
    int wave = t >> 6, lane = t & 63;
    int lrow   = lane >> 3;              // 0..7; == row&7 for my staged rows
    int schunk = (lane & 7) ^ lrow;      // inverse-swizzled source 16B chunk

    // staging: call q in {0,1}; row = q*32 + wave*8 + lrow  (row&7 == lrow)
    const short* aQ[2];
    const short* bQ[2];
    #pragma unroll
    for (int q = 0; q < 2; ++q) {
        int row = q * 32 + wave * 8 + lrow;
        int gr = row_lo + row;
        if (V >= 2 && gr >= row_hi) gr = row_lo; // clamp (epilogue guards)
        const short* arow;
        if (V == 2) arow = A + (size_t)(tok_map[gr] & (NTOK - 1)) * K;
        else        arow = A + (size_t)gr * K;
        aQ[q] = arow + (schunk << 3);
        bQ[q] = Bte + (size_t)(col0 + row) * K + (schunk << 3);
    }

    int rin = lane & 15, quad = lane >> 4;
    int wm = (wave & 1) * 32, wn = (wave >> 1) * 32;

    // ---- epilogue operand prefetch (keeps main loop free of stray VMEM) ----
    int cg0 = col0 + wn + rin;
    int cg1 = cg0 + 16;
    float bj[2] = { be[cg0], be[cg1] };
    float resv[2][2][4];
    if (V == 1) {
        #pragma unroll
        for (int i = 0; i < 2; ++i)
            #pragma unroll
            for (int j = 0; j < 2; ++j)
                #pragma unroll
                for (int rr = 0; rr < 4; ++rr)
                    resv[i][j][rr] = res[(size_t)(row_lo + wm + i*16 + quad*4 + rr) * M
                                         + (j ? cg1 : cg0)];
    }
    int   tmv[2][4];
    float tgv[2][4];
    if (V == 3) {
        #pragma unroll
        for (int i = 0; i < 2; ++i)
            #pragma unroll
            for (int rr = 0; rr < 4; ++rr) {
                int rg = row_lo + wm + i*16 + quad*4 + rr;
                tmv[i][rr] = tok_map[rg] & (NTOK - 1);
                tgv[i][rr] = tok_gate[rg];
            }
    }

    floatx4 acc[2][2];
    #pragma unroll
    for (int i = 0; i < 2; ++i)
        #pragma unroll
        for (int j = 0; j < 2; ++j)
            acc[i][j] = (floatx4){0.f, 0.f, 0.f, 0.f};

    const int NIT = K >> 6;

    // prologue: stage tile 0 -> buf0, tile 1 -> buf1 (8 loads/thread)
    #pragma unroll
    for (int q = 0; q < 2; ++q) {
        gld16(aQ[q], &As[(q * 32 + wave * 8) * BKS]);
        gld16(bQ[q], &Bs[(q * 32 + wave * 8) * BKS]);
    }
    if (NIT > 1) {
        #pragma unroll
        for (int q = 0; q < 2; ++q) {
            gld16(aQ[q] + 64, &As[BUFS + (q * 32 + wave * 8) * BKS]);
            gld16(bQ[q] + 64, &Bs[BUFS + (q * 32 + wave * 8) * BKS]);
        }
        asm volatile("s_waitcnt vmcnt(4)\n\ts_barrier" ::: "memory");
    } else {
        asm volatile("s_waitcnt vmcnt(0)\n\ts_barrier" ::: "memory");
    }
    __builtin_amdgcn_sched_barrier(0);

    int bread = 0;
    for (int it = 0; it < NIT; ++it) {
        if (it + 2 < NIT) {                  // stage tile it+2 (4 loads/thread)
            int bst = bread + 2; if (bst >= 3) bst -= 3;
            int kk = (it + 2) << 6;
            #pragma unroll
            for (int q = 0; q < 2; ++q) {
                gld16(aQ[q] + kk, &As[bst * BUFS + (q * 32 + wave * 8) * BKS]);
                gld16(bQ[q] + kk, &Bs[bst * BUFS + (q * 32 + wave * 8) * BKS]);
            }
        }
        const short* Ab = &As[bread * BUFS];
        const short* Bb = &Bs[bread * BUFS];
        #pragma unroll
        for (int s = 0; s < 2; ++s) {
            bf16x8 af[2], bfr[2];
            #pragma unroll
            for (int i = 0; i < 2; ++i) {
                int row = wm + i * 16 + rin;
                af[i] = *(const bf16x8*)&Ab[row * BKS
                        + ((((s << 2) | quad) ^ (rin & 7)) << 3)];
            }
            #pragma unroll
            for (int j = 0; j < 2; ++j) {
                int row = wn + j * 16 + rin;
                bfr[j] = *(const bf16x8*)&Bb[row * BKS
                        + ((((s << 2) | quad) ^ (rin & 7)) << 3)];
            }
            #pragma unroll
            for (int i = 0; i < 2; ++i)
                #pragma unroll
                for (int j = 0; j < 2; ++j)
                    acc[i][j] = __builtin_amdgcn_mfma_f32_16x16x32_bf16(
                        af[i], bfr[j], acc[i][j], 0, 0, 0);
        }
        if (it + 1 < NIT) {
            // need tile it+1 (issued last iter / prologue) complete; keep the
            // 4 newest (tile it+2) in flight when they exist.
            if (it + 2 < NIT)
                asm volatile("s_waitcnt vmcnt(4)\n\ts_barrier" ::: "memory");
            else
                asm volatile("s_waitcnt vmcnt(0)\n\ts_barrier" ::: "memory");
            __builtin_amdgcn_sched_barrier(0);
        }
        bread = bread + 1; if (bread >= 3) bread = 0;
    }

    // Epilogue. C/D layout: col = lane&15, row = quad*4 + reg  [m89-verified]
    #pragma unroll
    for (int i = 0; i < 2; ++i) {
        #pragma unroll
        for (int j = 0; j < 2; ++j) {
            int cg = j ? cg1 : cg0;
            #pragma unroll
            for (int rr = 0; rr < 4; ++rr) {
                int rg = row_lo + wm + i * 16 + quad * 4 + rr;
                float val = acc[i][j][rr];
                if (V == 0) {
                    C[(size_t)rg * M + cg] = val + bj[j];
                } else if (V == 1) {
                    C[(size_t)rg * M + cg] = val + bj[j] + resv[i][j][rr];
                } else if (V == 2) {
                    if (rg < row_hi) {
                        float vb_ = val + bj[j];
                        Cb[(size_t)rg * M + cg] = f2bf(vb_ / (1.f + __expf(-vb_)));
                    }
                } else {
                    if (rg < row_hi)
                        unsafeAtomicAdd(&C[(size_t)tmv[i][rr] * M + cg],
                                        tgv[i][rr] * (val + bj[j]));
                }
            }
        }
    }
}

// ---------------------------------------------------------------------------
// Sliding-window attention — fp32 math, conflict-free LDS (R5-proven)
// ---------------------------------------------------------------------------
__global__ __launch_bounds__(256) void attn_kernel(
    const float* __restrict__ qkv, const float* __restrict__ sink_ptr,
    short* __restrict__ ao)
{
    __shared__ __align__(16) float KT[32 * KPITCH * 4];
    __shared__ __align__(16) float Vs[WROWS * VPADF];
    __shared__ __align__(16) float Ps4[4][64][4];

    int qblk = blockIdx.x;
    int kvh  = blockIdx.y;
    int q0   = qblk * QB;
    int jbase = q0 - (WS_ - 1);

    int t = threadIdx.x;
    int c4 = (t & 31) * 4, c4g = t & 31;
    for (int r = t >> 5; r < WROWS; r += 8) {
        int j = jbase + r;
        float4 kv4 = make_float4(0.f, 0.f, 0.f, 0.f);
        float4 vv4 = make_float4(0.f, 0.f, 0.f, 0.f);
        if (j >= 0) {
            kv4 = *(const float4*)(qkv + (size_t)j * QKV_M + KOFF + kvh * HD + c4);
            vv4 = *(const float4*)(qkv + (size_t)j * QKV_M + VOFF + kvh * HD + c4);
        }
        *(float4*)&KT[(c4g * KPITCH + r) * 4] = kv4;
        *(float4*)&Vs[r * VPADF + c4] = vv4;
    }
    __syncthreads();

    int lane = t & 63, wv = t >> 6;
    float sink = sink_ptr[0];
    const float rscale = 0.08838834764831845f;

    #pragma unroll
    for (int g = 0; g < 2; ++g) {
        int qi = wv * 2 + g;
        int i  = q0 + qi;
        bool valid = (jbase + qi + lane) >= 0;

        float sc[4] = {0.f, 0.f, 0.f, 0.f};
        const float* qbase = qkv + (size_t)i * QKV_M + (kvh * 4) * HD;
        #pragma unroll
        for (int c = 0; c < 32; ++c) {
            float4 kx = *(const float4*)&KT[(c * KPITCH + qi + lane) * 4];
            #pragma unroll
            for (int hh = 0; hh < 4; ++hh) {
                float4 q4 = *(const float4*)(qbase + hh * HD + c * 4);
                sc[hh] += q4.x*kx.x + q4.y*kx.y + q4.z*kx.z + q4.w*kx.w;
            }
        }

        float pn[4];
        #pragma unroll
        for (int hh = 0; hh < 4; ++hh) {
            float s = valid ? sc[hh] * rscale : -1e30f;
            float m = s;
            #pragma unroll
            for (int off = 32; off; off >>= 1) m = fmaxf(m, __shfl_xor(m, off, 64));
            float mf = fmaxf(m, sink);
            float p  = __expf(s - mf);
            float ds = p;
            #pragma unroll
            for (int off = 32; off; off >>= 1) ds += __shfl_xor(ds, off, 64);
            pn[hh] = p / (ds + __expf(sink - mf));
        }
        *(float4*)&Ps4[wv][lane][0] = make_float4(pn[0], pn[1], pn[2], pn[3]);

        float o0=0,o1=0,o2=0,o3=0,o4=0,o5=0,o6=0,o7=0;
        const float* vp = &Vs[qi * VPADF + 2 * lane];
        #pragma unroll
        for (int jj = 0; jj < 64; ++jj) {
            float4 p4 = *(const float4*)&Ps4[wv][jj][0];
            float2 vv = *(const float2*)(vp + jj * VPADF);
            o0 += p4.x * vv.x; o1 += p4.x * vv.y;
            o2 += p4.y * vv.x; o3 += p4.y * vv.y;
            o4 += p4.z * vv.x; o5 += p4.z * vv.y;
            o6 += p4.w * vv.x; o7 += p4.w * vv.y;
        }
        short2 r0; r0.x = f2bf(o0); r0.y = f2bf(o1);
        short2 r1; r1.x = f2bf(o2); r1.y = f2bf(o3);
        short2 r2; r2.x = f2bf(o4); r2.y = f2bf(o5);
        short2 r3; r3.x = f2bf(o6); r3.y = f2bf(o7);
        ((short2*)(ao + (size_t)i * D + (kvh * 4 + 0) * HD))[lane] = r0;
        ((short2*)(ao + (size_t)i * D + (kvh * 4 + 1) * HD))[lane] = r1;
        ((short2*)(ao + (size_t)i * D + (kvh * 4 + 2) * HD))[lane] = r2;
        ((short2*)(ao + (size_t)i * D + (kvh * 4 + 3) * HD))[lane] = r3;
    }
}

// ---------------------------------------------------------------------------
// Fused RMSNorm2 + router; pre-initializes out = x1; accumulates expert
// column-sums (for aux) and histogram via device atomics (probs array gone).
// ---------------------------------------------------------------------------
__global__ __launch_bounds__(256) void rms_router_kernel(
    const float* __restrict__ x1, const float* __restrict__ w,
    short* __restrict__ h2b, const float* __restrict__ rwT,
    const float* __restrict__ rb, float* __restrict__ gcsum,
    int* __restrict__ ghist, int* __restrict__ top_i,
    float* __restrict__ top_g, float* __restrict__ out)
{
    int tok = blockIdx.x, t = threadIdx.x;
    __shared__ float hrow[D];
    float4 v = ((const float4*)(x1 + (size_t)tok * D))[t];
    ((float4*)(out + (size_t)tok * D))[t] = v;     // out = x1 (FFN added later)
    float ss = v.x*v.x + v.y*v.y + v.z*v.z + v.w*v.w;
    #pragma unroll
    for (int off = 32; off; off >>= 1) ss += __shfl_xor(ss, off, 64);
    __shared__ float red[4];
    if ((t & 63) == 0) red[t >> 6] = ss;
    __syncthreads();
    float total = red[0] + red[1] + red[2] + red[3];
    float scale = rsqrtf(total * (1.0f / (float)D) + 1e-6f);
    float4 wv = ((const float4*)w)[t];
    float4 o;
    o.x = v.x * scale * wv.x; o.y = v.y * scale * wv.y;
    o.z = v.z * scale * wv.z; o.w = v.w * scale * wv.w;
    ((float4*)hrow)[t] = o;
    short4 ob;
    ob.x = f2bf(o.x); ob.y = f2bf(o.y); ob.z = f2bf(o.z); ob.w = f2bf(o.w);
    ((short4*)(h2b + (size_t)tok * D))[t] = ob;
    __syncthreads();

    int e = t & 15, seg = t >> 4;
    const float4* rwp = (const float4*)(rwT + (size_t)e * D + seg * 64);
    const float4* hp  = (const float4*)(hrow + seg * 64);
    float part = 0.f;
    #pragma unroll
    for (int i = 0; i < 16; ++i) {
        float4 a = hp[i];
        float4 b = rwp[i];
        part += a.x * b.x; part += a.y * b.y;
        part += a.z * b.z; part += a.w * b.w;
    }
    __shared__ float lpart[256];
    lpart[t] = part;
    __syncthreads();
    __shared__ float logits[E_];
    if (t < E_) {
        float sl = 0.f;
        for (int sg = 0; sg < 16; ++sg) sl += lpart[sg * 16 + t];
        logits[t] = (sl + rb[t]) * 10.0f;   // /0.1
    }
    __syncthreads();
    __shared__ float sm[2];
    if (t == 0) {
        float mx = logits[0];
        for (int x_ = 1; x_ < E_; ++x_) mx = fmaxf(mx, logits[x_]);
        float ps = 0.f;
        for (int x_ = 0; x_ < E_; ++x_) ps += __expf(logits[x_] - mx);
        sm[0] = mx; sm[1] = ps;
        int i0 = 0; float v0 = logits[0];
        for (int x_ = 1; x_ < E_; ++x_) if (logits[x_] > v0) { v0 = logits[x_]; i0 = x_; }
        int i1 = (i0 == 0) ? 1 : 0; float v1 = logits[i1];
        for (int x_ = 0; x_ < E_; ++x_) {
            if (x_ == i0) continue;
            if (logits[x_] > v1) { v1 = logits[x_]; i1 = x_; }
        }
        float e1 = __expf(v1 - v0);
        float g0 = 1.f / (1.f + e1);
        float g1 = e1 * g0;
        top_i[tok * 2 + 0] = i0; top_g[tok * 2 + 0] = g0;
        top_i[tok * 2 + 1] = i1; top_g[tok * 2 + 1] = g1;
        atomicAdd(&ghist[i0], 1);
        atomicAdd(&ghist[i1], 1);
    }
    __syncthreads();
    if (t < E_)
        unsafeAtomicAdd(&gcsum[t], __expf(logits[t] - sm[0]) / sm[1]);
}

// ---------------------------------------------------------------------------
// Finalize + scatter (single block): offs prefix + aux from gcsum/ghist;
// scatter slots expert-contiguously with LDS cursors + inverse slot map.
// ---------------------------------------------------------------------------
__global__ __launch_bounds__(256) void finalize_scatter_kernel(
    const float* __restrict__ gcsum, const int* __restrict__ ghist,
    const int* __restrict__ top_i, const float* __restrict__ top_g,
    int* __restrict__ offs, int* __restrict__ tok_idx,
    float* __restrict__ tok_gate, int* __restrict__ slot_of,
    float* __restrict__ aux_out)
{
    __shared__ int curs[E_];
    int t = threadIdx.x;
    if (t == 0) {
        int acc = 0;
        for (int e = 0; e < E_; ++e) { offs[e] = acc; curs[e] = acc; acc += ghist[e]; }
        offs[E_] = acc;
        float s = 0.f;
        for (int e = 0; e < E_; ++e) { float c = gcsum[e]; s += c * c; }
        *aux_out = s / (float)E_ * 1e-5f;
    }
    __syncthreads();

    for (int i = 0; i < NTOK / 256; ++i) {
        int tok = i * 256 + t;
        #pragma unroll
        for (int s = 0; s < TOPK; ++s) {
            int e = top_i[tok * 2 + s] & 15;  // mask: insurance vs NaN logits
            int pos = atomicAdd(&curs[e], 1) & (NSLOT - 1);
            tok_idx[pos]  = tok;
            tok_gate[pos] = top_g[tok * 2 + s];
            slot_of[tok * 2 + s] = pos;
        }
    }
}

// ---------------------------------------------------------------------------
extern "C" void kernel_launch(void* const* d_in, const int* in_sizes, int n_in,
                              void* d_out, int out_size, void* d_ws, size_t ws_size,
                              hipStream_t stream)
{
    const float* x        = (const float*)d_in[0];
    const float* norm1_w  = (const float*)d_in[1];
    const float* wq       = (const float*)d_in[2];
    const float* bq       = (const float*)d_in[3];
    const float* wk       = (const float*)d_in[4];
    const float* bk       = (const float*)d_in[5];
    const float* wv       = (const float*)d_in[6];
    const float* bv       = (const float*)d_in[7];
    const float* wo       = (const float*)d_in[8];
    const float* bo       = (const float*)d_in[9];
    const float* sink     = (const float*)d_in[10];
    const float* norm2_w  = (const float*)d_in[11];
    const float* router_w = (const float*)d_in[12];
    const float* router_b = (const float*)d_in[13];
    const float* w1       = (const float*)d_in[14];
    const float* b1       = (const float*)d_in[15];
    const float* w2       = (const float*)d_in[16];
    const float* b2       = (const float*)d_in[17];
    float* out = (float*)d_out;

    // workspace layout
    char* w = (char*)d_ws;
    auto alloc = [&](size_t bytes) {
        char* p = w; w += (bytes + 255) & ~255ull; return p;
    };
    short* wqkvT = (short*)alloc((size_t)QKV_M * D * 2);
    short* woT   = (short*)alloc((size_t)D * D * 2);
    short* w1T   = (short*)alloc((size_t)E_ * HDIM * D * 2);
    short* w2T   = (short*)alloc((size_t)E_ * D * HDIM * 2);
    float* bqkv  = (float*)alloc(QKV_M * 4);
    float* rwT   = (float*)alloc((size_t)E_ * D * 4);
    short* h_bf  = (short*)alloc((size_t)S * D * 2);
    float* qkv   = (float*)alloc((size_t)S * QKV_M * 4);
    float* x1    = (float*)alloc((size_t)S * D * 4);
    short* h2b   = (short*)alloc((size_t)S * D * 2);
    float* gcsum = (float*)alloc(E_ * 4);
    int*   ghist = (int*)alloc(E_ * 4);
    int*   offs     = (int*)alloc(17 * 4);
    int*   top_i    = (int*)alloc((size_t)NSLOT * 4);
    float* top_g    = (float*)alloc((size_t)NSLOT * 4);
    int*   tok_idx  = (int*)alloc((size_t)NSLOT * 4);
    float* tok_gate = (float*)alloc((size_t)NSLOT * 4);
    int*   slot_of  = (int*)alloc((size_t)NSLOT * 4);
    // aliases (lifetimes don't overlap):
    short* ao_bf = h_bf;          // h_bf dead after QKV GEMM
    short* hmid  = (short*)qkv;   // qkv dead after attention

    // 0) all weight prep + rmsnorm(x) + accumulator zero-init in one launch
    tconv_all<<<21031, 256, 0, stream>>>(wq, wk, wv, wo, w1, w2, bq, bk, bv,
                                         router_w, wqkvT, woT, w1T, w2T,
                                         bqkv, rwT, x, norm1_w, h_bf,
                                         gcsum, ghist);

    // 1) fused QKV   (24 x 32 = 768 blocks)
    mgemm<0><<<dim3(QKV_M / BT, S / BT), 256, 0, stream>>>(
        h_bf, wqkvT, bqkv, qkv, nullptr, nullptr, D, QKV_M, nullptr, nullptr,
        nullptr);

    // 2) attention -> bf16 ao
    attn_kernel<<<dim3(S / QB, NKV), 256, 0, stream>>>(qkv, sink, ao_bf);

    // 3) x1 = x + ao@wo + bo   (16 x 32 = 512 blocks)
    mgemm<1><<<dim3(D / BT, S / BT), 256, 0, stream>>>(
        ao_bf, woT, bo, x1, nullptr, x, D, D, nullptr, nullptr, nullptr);

    // 4) fused rmsnorm2 + router; pre-init out = x1; csum/hist atomics
    rms_router_kernel<<<NTOK, 256, 0, stream>>>(x1, norm2_w, h2b, rwT,
                                                router_b, gcsum, ghist,
                                                top_i, top_g, out);

    // 5) finalize + scatter (LDS cursors)
    finalize_scatter_kernel<<<1, 256, 0, stream>>>(
        gcsum, ghist, top_i, top_g, offs, tok_idx, tok_gate, slot_of,
        out + (size_t)S * D);

    // 6) MoE GEMM1 (gather fused: A rows = h2b[tok_idx[slot]])
    mgemm<2><<<dim3(HDIM / BT, NSLOT / BT, E_), 256, 0, stream>>>(
        h2b, w1T, b1, nullptr, hmid, nullptr, D, HDIM, offs, nullptr, tok_idx);

    // 7) MoE GEMM2 (combine fused: atomic out[tok] += gate*(val+bias))
    mgemm<3><<<dim3(D / BT, NSLOT / BT, E_), 256, 0, stream>>>(
        hmid, w2T, b2, out, nullptr, nullptr, HDIM, D, offs, tok_gate, tok_idx);
}

// Round 5
// 275.486 us; speedup vs baseline: 1.1130x; 1.1130x over previous
//
#include <hip/hip_runtime.h>
#include <hip/hip_bf16.h>

// Problem constants
#define S     2048
#define D     1024
#define NH    8
#define NKV   2
#define HD    128
#define WS_   64
#define E_    16
#define HDIM  512
#define TOPK  2
#define NTOK  S
#define NSLOT (S*TOPK)         // 4096
#define QKV_M (D + 2*NKV*HD)   // 1536 fused q|k|v columns
#define KOFF  D                // 1024
#define VOFF  (D + NKV*HD)     // 1280
#define QB    8                // queries per attention block
#define WROWS (QB + WS_ - 1)   // 71 key rows per window
#define KPITCH 73              // KT key pitch (float4 units)
#define VPADF  132             // Vs row stride in floats

typedef __attribute__((ext_vector_type(8))) short bf16x8;
typedef __attribute__((ext_vector_type(4))) float floatx4;

__device__ inline short f2bf(float f) {
    __hip_bfloat16 b = __float2bfloat16(f);
    return *reinterpret_cast<short*>(&b);
}

// ---------------------------------------------------------------------------
// All weight prep + attention pre-norm in ONE launch:
//   6 transpose+convert regions + bias concat + router_w transpose
//   + rmsnorm(x)->bf16 region (2048 blocks).
// ---------------------------------------------------------------------------
__global__ __launch_bounds__(256) void tconv_all(
    const float* __restrict__ wq, const float* __restrict__ wk,
    const float* __restrict__ wv, const float* __restrict__ wo,
    const float* __restrict__ w1, const float* __restrict__ w2,
    const float* __restrict__ bq, const float* __restrict__ bk,
    const float* __restrict__ bv, const float* __restrict__ router_w,
    short* __restrict__ wqkvT, short* __restrict__ woT,
    short* __restrict__ w1T, short* __restrict__ w2T,
    float* __restrict__ bqkv, float* __restrict__ rwT,
    const float* __restrict__ x, const float* __restrict__ norm1_w,
    short* __restrict__ h_bf)
{
    int id = blockIdx.x;
    if (id >= 18982) {                       // 2048 rmsnorm blocks
        int row = id - 18982, t = threadIdx.x;
        float4 v = ((const float4*)(x + (size_t)row * D))[t];
        float ss = v.x*v.x + v.y*v.y + v.z*v.z + v.w*v.w;
        #pragma unroll
        for (int off = 32; off; off >>= 1) ss += __shfl_xor(ss, off, 64);
        __shared__ float red[4];
        if ((t & 63) == 0) red[t >> 6] = ss;
        __syncthreads();
        float total = red[0] + red[1] + red[2] + red[3];
        float scale = rsqrtf(total * (1.0f / (float)D) + 1e-6f);
        float4 wv4 = ((const float4*)norm1_w)[t];
        short4 ob;
        ob.x = f2bf(v.x * scale * wv4.x); ob.y = f2bf(v.y * scale * wv4.y);
        ob.z = f2bf(v.z * scale * wv4.z); ob.w = f2bf(v.w * scale * wv4.w);
        ((short4*)(h_bf + (size_t)row * D))[t] = ob;
        return;
    }
    if (id >= 18950) {                       // 32 router_w transpose blocks
        int ky = id - 18950;                 // 0..31
        int t = threadIdx.x;
        int r = t >> 4, c = t & 15;
        int k0 = ky * 32;
        rwT[c * D + k0 + r]      = router_w[(k0 + r) * E_ + c];
        rwT[c * D + k0 + r + 16] = router_w[(k0 + r + 16) * E_ + c];
        return;
    }
    if (id >= 18944) {                       // 6 bias-concat blocks
        int t = (id - 18944) * 256 + threadIdx.x;
        if (t < D) bqkv[t] = bq[t];
        else if (t < VOFF) bqkv[t] = bk[t - D];
        else bqkv[t] = bv[t - VOFF];
        return;
    }
    const float* in; short* outp; int K, M, mx, ky;
    if (id < 1024)      { in = wq; outp = wqkvT;                  K = D; M = D;   int l = id;        mx = l & 31; ky = l >> 5; }
    else if (id < 1280) { in = wk; outp = wqkvT + (size_t)KOFF*D; K = D; M = 256; int l = id - 1024; mx = l & 7;  ky = l >> 3; }
    else if (id < 1536) { in = wv; outp = wqkvT + (size_t)VOFF*D; K = D; M = 256; int l = id - 1280; mx = l & 7;  ky = l >> 3; }
    else if (id < 2560) { in = wo; outp = woT;                    K = D; M = D;   int l = id - 1536; mx = l & 31; ky = l >> 5; }
    else if (id < 10752){ int l = id - 2560;  int e = l >> 9; int r = l & 511;
                          in = w1 + (size_t)e * D * HDIM; outp = w1T + (size_t)e * D * HDIM;
                          K = D; M = HDIM; mx = r & 15; ky = r >> 4; }
    else                { int l = id - 10752; int e = l >> 9; int r = l & 511;
                          in = w2 + (size_t)e * D * HDIM; outp = w2T + (size_t)e * D * HDIM;
                          K = HDIM; M = D; mx = r & 31; ky = r >> 5; }
    __shared__ float tile[32][33];
    int t = threadIdx.x, r = t >> 3, c4 = (t & 7) * 4;
    int k0 = ky * 32, m0 = mx * 32;
    float4 v = *(const float4*)&in[(size_t)(k0 + r) * M + m0 + c4];
    tile[r][c4 + 0] = v.x; tile[r][c4 + 1] = v.y;
    tile[r][c4 + 2] = v.z; tile[r][c4 + 3] = v.w;
    __syncthreads();
    short4 o;
    o.x = f2bf(tile[c4 + 0][r]);
    o.y = f2bf(tile[c4 + 1][r]);
    o.z = f2bf(tile[c4 + 2][r]);
    o.w = f2bf(tile[c4 + 3][r]);
    *(short4*)&outp[(size_t)(m0 + r) * K + k0 + c4] = o;
}

// ---------------------------------------------------------------------------
// bf16 MFMA GEMM: 64x64 tile, BK=64, TRIPLE-buffered LDS (48 KB),
// global_load_lds width=16 staging issued TWO tiles ahead, raw s_barrier
// with COUNTED s_waitcnt vmcnt(4) (T4). Epilogue operands prefetched into
// registers BEFORE the loop. XOR involution swizzle source+read.
// MFMA accumulation order per output element identical -> numerics preserved.
// V=0: C fp32 (QKV)            V=1: +bias+res (WO->x1)
// V=2: MoE1 silu->bf16, A-rows indirect via tok_map (gather fused)
// V=3: MoE2 atomic-accumulate gate*(val+bias) into out[token] (combine fused)
// ---------------------------------------------------------------------------
#define BT   64
#define BKS  64                 // k shorts per step
#define BUFS (BT * BKS)         // 4096 shorts = 8 KB

__device__ inline void gld16(const short* g, short* l) {
    __builtin_amdgcn_global_load_lds(
        (const __attribute__((address_space(1))) unsigned int*)g,
        (__attribute__((address_space(3))) unsigned int*)l, 16, 0, 0);
}

template <int V>
__global__ __launch_bounds__(256) void mgemm(
    const short* __restrict__ A, const short* __restrict__ Bt,
    const float* __restrict__ bias, float* __restrict__ C,
    short* __restrict__ Cb, const float* __restrict__ res, int K, int M,
    const int* __restrict__ offs, const float* __restrict__ tok_gate,
    const int* __restrict__ tok_map)
{
    int e = (V >= 2) ? blockIdx.z : 0;
    const short* Bte = (V >= 2) ? Bt + (size_t)e * M * K : Bt;
    const float* be  = (V >= 2) ? bias + (size_t)e * M : bias;

    int row_lo, row_hi;
    if (V >= 2) {
        row_lo = offs[e] + blockIdx.y * BT;
        row_hi = offs[e + 1];
        if (row_lo >= row_hi) return;
    } else {
        row_lo = blockIdx.y * BT;
        row_hi = 1 << 30;
    }
    int col0 = blockIdx.x * BT;

    __shared__ __align__(16) short As[3 * BUFS];   // 24 KB
    __shared__ __align__(16) short Bs[3 * BUFS];   // 24 KB

    int t = threadIdx.x;
    int wave = t >> 6, lane = t & 63;
    int lrow   = lane >> 3;              // 0..7; == row&7 for my staged rows
    int schunk = (lane & 7) ^ lrow;      // inverse-swizzled source 16B chunk

    // staging: call q in {0,1}; row = q*32 + wave*8 + lrow  (row&7 == lrow)
    const short* aQ[2];
    const short* bQ[2];
    #pragma unroll
    for (int q = 0; q < 2; ++q) {
        int row = q * 32 + wave * 8 + lrow;
        int gr = row_lo + row;
        if (V >= 2 && gr >= row_hi) gr = row_lo; // clamp (epilogue guards)
        const short* arow;
        if (V == 2) arow = A + (size_t)(tok_map[gr] & (NTOK - 1)) * K;
        else        arow = A + (size_t)gr * K;
        aQ[q] = arow + (schunk << 3);
        bQ[q] = Bte + (size_t)(col0 + row) * K + (schunk << 3);
    }

    int rin = lane & 15, quad = lane >> 4;
    int wm = (wave & 1) * 32, wn = (wave >> 1) * 32;

    // ---- epilogue operand prefetch (keeps main loop free of stray VMEM) ----
    int cg0 = col0 + wn + rin;
    int cg1 = cg0 + 16;
    float bj[2] = { be[cg0], be[cg1] };
    float resv[2][2][4];
    if (V == 1) {
        #pragma unroll
        for (int i = 0; i < 2; ++i)
            #pragma unroll
            for (int j = 0; j < 2; ++j)
                #pragma unroll
                for (int rr = 0; rr < 4; ++rr)
                    resv[i][j][rr] = res[(size_t)(row_lo + wm + i*16 + quad*4 + rr) * M
                                         + (j ? cg1 : cg0)];
    }
    int   tmv[2][4];
    float tgv[2][4];
    if (V == 3) {
        #pragma unroll
        for (int i = 0; i < 2; ++i)
            #pragma unroll
            for (int rr = 0; rr < 4; ++rr) {
                int rg = row_lo + wm + i*16 + quad*4 + rr;
                tmv[i][rr] = tok_map[rg] & (NTOK - 1);
                tgv[i][rr] = tok_gate[rg];
            }
    }

    floatx4 acc[2][2];
    #pragma unroll
    for (int i = 0; i < 2; ++i)
        #pragma unroll
        for (int j = 0; j < 2; ++j)
            acc[i][j] = (floatx4){0.f, 0.f, 0.f, 0.f};

    const int NIT = K >> 6;

    // prologue: stage tile 0 -> buf0, tile 1 -> buf1 (8 loads/thread)
    #pragma unroll
    for (int q = 0; q < 2; ++q) {
        gld16(aQ[q], &As[(q * 32 + wave * 8) * BKS]);
        gld16(bQ[q], &Bs[(q * 32 + wave * 8) * BKS]);
    }
    if (NIT > 1) {
        #pragma unroll
        for (int q = 0; q < 2; ++q) {
            gld16(aQ[q] + 64, &As[BUFS + (q * 32 + wave * 8) * BKS]);
            gld16(bQ[q] + 64, &Bs[BUFS + (q * 32 + wave * 8) * BKS]);
        }
        asm volatile("s_waitcnt vmcnt(4)\n\ts_barrier" ::: "memory");
    } else {
        asm volatile("s_waitcnt vmcnt(0)\n\ts_barrier" ::: "memory");
    }
    __builtin_amdgcn_sched_barrier(0);

    int bread = 0;
    for (int it = 0; it < NIT; ++it) {
        if (it + 2 < NIT) {                  // stage tile it+2 (4 loads/thread)
            int bst = bread + 2; if (bst >= 3) bst -= 3;
            int kk = (it + 2) << 6;
            #pragma unroll
            for (int q = 0; q < 2; ++q) {
                gld16(aQ[q] + kk, &As[bst * BUFS + (q * 32 + wave * 8) * BKS]);
                gld16(bQ[q] + kk, &Bs[bst * BUFS + (q * 32 + wave * 8) * BKS]);
            }
        }
        const short* Ab = &As[bread * BUFS];
        const short* Bb = &Bs[bread * BUFS];
        #pragma unroll
        for (int s = 0; s < 2; ++s) {
            bf16x8 af[2], bfr[2];
            #pragma unroll
            for (int i = 0; i < 2; ++i) {
                int row = wm + i * 16 + rin;
                af[i] = *(const bf16x8*)&Ab[row * BKS
                        + ((((s << 2) | quad) ^ (rin & 7)) << 3)];
            }
            #pragma unroll
            for (int j = 0; j < 2; ++j) {
                int row = wn + j * 16 + rin;
                bfr[j] = *(const bf16x8*)&Bb[row * BKS
                        + ((((s << 2) | quad) ^ (rin & 7)) << 3)];
            }
            #pragma unroll
            for (int i = 0; i < 2; ++i)
                #pragma unroll
                for (int j = 0; j < 2; ++j)
                    acc[i][j] = __builtin_amdgcn_mfma_f32_16x16x32_bf16(
                        af[i], bfr[j], acc[i][j], 0, 0, 0);
        }
        if (it + 1 < NIT) {
            if (it + 2 < NIT)
                asm volatile("s_waitcnt vmcnt(4)\n\ts_barrier" ::: "memory");
            else
                asm volatile("s_waitcnt vmcnt(0)\n\ts_barrier" ::: "memory");
            __builtin_amdgcn_sched_barrier(0);
        }
        bread = bread + 1; if (bread >= 3) bread = 0;
    }

    // Epilogue. C/D layout: col = lane&15, row = quad*4 + reg  [m89-verified]
    #pragma unroll
    for (int i = 0; i < 2; ++i) {
        #pragma unroll
        for (int j = 0; j < 2; ++j) {
            int cg = j ? cg1 : cg0;
            #pragma unroll
            for (int rr = 0; rr < 4; ++rr) {
                int rg = row_lo + wm + i * 16 + quad * 4 + rr;
                float val = acc[i][j][rr];
                if (V == 0) {
                    C[(size_t)rg * M + cg] = val + bj[j];
                } else if (V == 1) {
                    C[(size_t)rg * M + cg] = val + bj[j] + resv[i][j][rr];
                } else if (V == 2) {
                    if (rg < row_hi) {
                        float vb_ = val + bj[j];
                        Cb[(size_t)rg * M + cg] = f2bf(vb_ / (1.f + __expf(-vb_)));
                    }
                } else {
                    if (rg < row_hi)
                        unsafeAtomicAdd(&C[(size_t)tmv[i][rr] * M + cg],
                                        tgv[i][rr] * (val + bj[j]));
                }
            }
        }
    }
}

// ---------------------------------------------------------------------------
// Sliding-window attention — fp32 math, conflict-free LDS (R5-proven)
// ---------------------------------------------------------------------------
__global__ __launch_bounds__(256) void attn_kernel(
    const float* __restrict__ qkv, const float* __restrict__ sink_ptr,
    short* __restrict__ ao)
{
    __shared__ __align__(16) float KT[32 * KPITCH * 4];
    __shared__ __align__(16) float Vs[WROWS * VPADF];
    __shared__ __align__(16) float Ps4[4][64][4];

    int qblk = blockIdx.x;
    int kvh  = blockIdx.y;
    int q0   = qblk * QB;
    int jbase = q0 - (WS_ - 1);

    int t = threadIdx.x;
    int c4 = (t & 31) * 4, c4g = t & 31;
    for (int r = t >> 5; r < WROWS; r += 8) {
        int j = jbase + r;
        float4 kv4 = make_float4(0.f, 0.f, 0.f, 0.f);
        float4 vv4 = make_float4(0.f, 0.f, 0.f, 0.f);
        if (j >= 0) {
            kv4 = *(const float4*)(qkv + (size_t)j * QKV_M + KOFF + kvh * HD + c4);
            vv4 = *(const float4*)(qkv + (size_t)j * QKV_M + VOFF + kvh * HD + c4);
        }
        *(float4*)&KT[(c4g * KPITCH + r) * 4] = kv4;
        *(float4*)&Vs[r * VPADF + c4] = vv4;
    }
    __syncthreads();

    int lane = t & 63, wv = t >> 6;
    float sink = sink_ptr[0];
    const float rscale = 0.08838834764831845f;

    #pragma unroll
    for (int g = 0; g < 2; ++g) {
        int qi = wv * 2 + g;
        int i  = q0 + qi;
        bool valid = (jbase + qi + lane) >= 0;

        float sc[4] = {0.f, 0.f, 0.f, 0.f};
        const float* qbase = qkv + (size_t)i * QKV_M + (kvh * 4) * HD;
        #pragma unroll
        for (int c = 0; c < 32; ++c) {
            float4 kx = *(const float4*)&KT[(c * KPITCH + qi + lane) * 4];
            #pragma unroll
            for (int hh = 0; hh < 4; ++hh) {
                float4 q4 = *(const float4*)(qbase + hh * HD + c * 4);
                sc[hh] += q4.x*kx.x + q4.y*kx.y + q4.z*kx.z + q4.w*kx.w;
            }
        }

        float pn[4];
        #pragma unroll
        for (int hh = 0; hh < 4; ++hh) {
            float s = valid ? sc[hh] * rscale : -1e30f;
            float m = s;
            #pragma unroll
            for (int off = 32; off; off >>= 1) m = fmaxf(m, __shfl_xor(m, off, 64));
            float mf = fmaxf(m, sink);
            float p  = __expf(s - mf);
            float ds = p;
            #pragma unroll
            for (int off = 32; off; off >>= 1) ds += __shfl_xor(ds, off, 64);
            pn[hh] = p / (ds + __expf(sink - mf));
        }
        *(float4*)&Ps4[wv][lane][0] = make_float4(pn[0], pn[1], pn[2], pn[3]);

        float o0=0,o1=0,o2=0,o3=0,o4=0,o5=0,o6=0,o7=0;
        const float* vp = &Vs[qi * VPADF + 2 * lane];
        #pragma unroll
        for (int jj = 0; jj < 64; ++jj) {
            float4 p4 = *(const float4*)&Ps4[wv][jj][0];
            float2 vv = *(const float2*)(vp + jj * VPADF);
            o0 += p4.x * vv.x; o1 += p4.x * vv.y;
            o2 += p4.y * vv.x; o3 += p4.y * vv.y;
            o4 += p4.z * vv.x; o5 += p4.z * vv.y;
            o6 += p4.w * vv.x; o7 += p4.w * vv.y;
        }
        short2 r0; r0.x = f2bf(o0); r0.y = f2bf(o1);
        short2 r1; r1.x = f2bf(o2); r1.y = f2bf(o3);
        short2 r2; r2.x = f2bf(o4); r2.y = f2bf(o5);
        short2 r3; r3.x = f2bf(o6); r3.y = f2bf(o7);
        ((short2*)(ao + (size_t)i * D + (kvh * 4 + 0) * HD))[lane] = r0;
        ((short2*)(ao + (size_t)i * D + (kvh * 4 + 1) * HD))[lane] = r1;
        ((short2*)(ao + (size_t)i * D + (kvh * 4 + 2) * HD))[lane] = r2;
        ((short2*)(ao + (size_t)i * D + (kvh * 4 + 3) * HD))[lane] = r3;
    }
}

// ---------------------------------------------------------------------------
// Fused RMSNorm2 + router; pre-initializes out = x1. Router tail is
// lane-parallel (16 lanes via shuffles; no serial t==0 section, no global
// atomics — R4's same-cacheline atomics were a 25 µs regression).
// ---------------------------------------------------------------------------
__global__ __launch_bounds__(256) void rms_router_kernel(
    const float* __restrict__ x1, const float* __restrict__ w,
    short* __restrict__ h2b, const float* __restrict__ rwT,
    const float* __restrict__ rb, float* __restrict__ probs,
    int* __restrict__ top_i, float* __restrict__ top_g,
    float* __restrict__ out)
{
    int tok = blockIdx.x, t = threadIdx.x;
    __shared__ float hrow[D];
    float4 v = ((const float4*)(x1 + (size_t)tok * D))[t];
    ((float4*)(out + (size_t)tok * D))[t] = v;     // out = x1 (FFN added later)
    float ss = v.x*v.x + v.y*v.y + v.z*v.z + v.w*v.w;
    #pragma unroll
    for (int off = 32; off; off >>= 1) ss += __shfl_xor(ss, off, 64);
    __shared__ float red[4];
    if ((t & 63) == 0) red[t >> 6] = ss;
    __syncthreads();
    float total = red[0] + red[1] + red[2] + red[3];
    float scale = rsqrtf(total * (1.0f / (float)D) + 1e-6f);
    float4 wv = ((const float4*)w)[t];
    float4 o;
    o.x = v.x * scale * wv.x; o.y = v.y * scale * wv.y;
    o.z = v.z * scale * wv.z; o.w = v.w * scale * wv.w;
    ((float4*)hrow)[t] = o;
    short4 ob;
    ob.x = f2bf(o.x); ob.y = f2bf(o.y); ob.z = f2bf(o.z); ob.w = f2bf(o.w);
    ((short4*)(h2b + (size_t)tok * D))[t] = ob;
    __syncthreads();

    int e = t & 15, seg = t >> 4;
    const float4* rwp = (const float4*)(rwT + (size_t)e * D + seg * 64);
    const float4* hp  = (const float4*)(hrow + seg * 64);
    float part = 0.f;
    #pragma unroll
    for (int i = 0; i < 16; ++i) {
        float4 a = hp[i];
        float4 b = rwp[i];
        part += a.x * b.x; part += a.y * b.y;
        part += a.z * b.z; part += a.w * b.w;
    }
    __shared__ float lpart[256];
    lpart[t] = part;
    __syncthreads();

    if (t < E_) {
        float sl = 0.f;
        #pragma unroll
        for (int sg = 0; sg < 16; ++sg) sl += lpart[sg * 16 + t];
        float lv = (sl + rb[t]) * 10.0f;   // /0.1

        // lane-parallel argmax (value desc, index asc tie-break = reference)
        float bv = lv; int bi = t;
        #pragma unroll
        for (int off = 8; off; off >>= 1) {
            float ov = __shfl_xor(bv, off, 16);
            int   oi = __shfl_xor(bi, off, 16);
            if (ov > bv || (ov == bv && oi < bi)) { bv = ov; bi = oi; }
        }
        // second max excluding bi
        float lv2 = (t == bi) ? -3.402823e38f : lv;
        float bv2 = lv2; int bi2 = t;
        #pragma unroll
        for (int off = 8; off; off >>= 1) {
            float ov = __shfl_xor(bv2, off, 16);
            int   oi = __shfl_xor(bi2, off, 16);
            if (ov > bv2 || (ov == bv2 && oi < bi2)) { bv2 = ov; bi2 = oi; }
        }
        // softmax denom over all 16 (max = bv)
        float pexp = __expf(lv - bv);
        float ps = pexp;
        #pragma unroll
        for (int off = 8; off; off >>= 1) ps += __shfl_xor(ps, off, 16);
        probs[tok * E_ + t] = pexp / ps;
        if (t == 0) {
            float e1 = __expf(bv2 - bv);
            float g0 = 1.f / (1.f + e1);
            top_i[tok * 2 + 0] = bi;  top_g[tok * 2 + 0] = g0;
            top_i[tok * 2 + 1] = bi2; top_g[tok * 2 + 1] = e1 * g0;
        }
    }
}

// ---------------------------------------------------------------------------
// Finalize + scatter (single block, LDS cursors): colsum+aux from probs;
// histogram from top_i; offs; scatter slots expert-contiguously.
// ---------------------------------------------------------------------------
__global__ __launch_bounds__(256) void finalize_scatter_kernel(
    const float* __restrict__ probs, const int* __restrict__ top_i,
    const float* __restrict__ top_g, int* __restrict__ offs,
    int* __restrict__ tok_idx, float* __restrict__ tok_gate,
    int* __restrict__ slot_of, float* __restrict__ aux_out)
{
    __shared__ float csum[E_];
    __shared__ int hist[E_];
    __shared__ int curs[E_];
    int t = threadIdx.x;
    if (t < E_) { csum[t] = 0.f; hist[t] = 0; }
    __syncthreads();

    int c = t & 15, g = t >> 4;
    float part = 0.f;
    for (int i = 0; i < NTOK / 16; ++i)
        part += probs[(size_t)(i * 16 + g) * E_ + c];
    atomicAdd(&csum[c], part);

    for (int i = 0; i < NSLOT / 256; ++i) {
        int eidx = top_i[i * 256 + t] & 15;   // mask: never index OOB
        atomicAdd(&hist[eidx], 1);
    }
    __syncthreads();

    if (t == 0) {
        int acc = 0;
        for (int e = 0; e < E_; ++e) { offs[e] = acc; curs[e] = acc; acc += hist[e]; }
        offs[E_] = acc;
        float s = 0.f;
        for (int e = 0; e < E_; ++e) s += csum[e] * csum[e];
        *aux_out = s / (float)E_ * 1e-5f;
    }
    __syncthreads();

    for (int i = 0; i < NTOK / 256; ++i) {
        int tok = i * 256 + t;
        #pragma unroll
        for (int s = 0; s < TOPK; ++s) {
            int e = top_i[tok * 2 + s] & 15;  // mask: insurance vs NaN logits
            int pos = atomicAdd(&curs[e], 1) & (NSLOT - 1);
            tok_idx[pos]  = tok;
            tok_gate[pos] = top_g[tok * 2 + s];
            slot_of[tok * 2 + s] = pos;
        }
    }
}

// ---------------------------------------------------------------------------
extern "C" void kernel_launch(void* const* d_in, const int* in_sizes, int n_in,
                              void* d_out, int out_size, void* d_ws, size_t ws_size,
                              hipStream_t stream)
{
    const float* x        = (const float*)d_in[0];
    const float* norm1_w  = (const float*)d_in[1];
    const float* wq       = (const float*)d_in[2];
    const float* bq       = (const float*)d_in[3];
    const float* wk       = (const float*)d_in[4];
    const float* bk       = (const float*)d_in[5];
    const float* wv       = (const float*)d_in[6];
    const float* bv       = (const float*)d_in[7];
    const float* wo       = (const float*)d_in[8];
    const float* bo       = (const float*)d_in[9];
    const float* sink     = (const float*)d_in[10];
    const float* norm2_w  = (const float*)d_in[11];
    const float* router_w = (const float*)d_in[12];
    const float* router_b = (const float*)d_in[13];
    const float* w1       = (const float*)d_in[14];
    const float* b1       = (const float*)d_in[15];
    const float* w2       = (const float*)d_in[16];
    const float* b2       = (const float*)d_in[17];
    float* out = (float*)d_out;

    // workspace layout
    char* w = (char*)d_ws;
    auto alloc = [&](size_t bytes) {
        char* p = w; w += (bytes + 255) & ~255ull; return p;
    };
    short* wqkvT = (short*)alloc((size_t)QKV_M * D * 2);
    short* woT   = (short*)alloc((size_t)D * D * 2);
    short* w1T   = (short*)alloc((size_t)E_ * HDIM * D * 2);
    short* w2T   = (short*)alloc((size_t)E_ * D * HDIM * 2);
    float* bqkv  = (float*)alloc(QKV_M * 4);
    float* rwT   = (float*)alloc((size_t)E_ * D * 4);
    short* h_bf  = (short*)alloc((size_t)S * D * 2);
    float* qkv   = (float*)alloc((size_t)S * QKV_M * 4);
    float* x1    = (float*)alloc((size_t)S * D * 4);
    short* h2b   = (short*)alloc((size_t)S * D * 2);
    float* probs = (float*)alloc((size_t)NTOK * E_ * 4);
    int*   offs     = (int*)alloc(17 * 4);
    int*   top_i    = (int*)alloc((size_t)NSLOT * 4);
    float* top_g    = (float*)alloc((size_t)NSLOT * 4);
    int*   tok_idx  = (int*)alloc((size_t)NSLOT * 4);
    float* tok_gate = (float*)alloc((size_t)NSLOT * 4);
    int*   slot_of  = (int*)alloc((size_t)NSLOT * 4);
    // aliases (lifetimes don't overlap):
    short* ao_bf = h_bf;          // h_bf dead after QKV GEMM
    short* hmid  = (short*)qkv;   // qkv dead after attention

    // 0) all weight prep + rmsnorm(x) in one launch
    tconv_all<<<21030, 256, 0, stream>>>(wq, wk, wv, wo, w1, w2, bq, bk, bv,
                                         router_w, wqkvT, woT, w1T, w2T,
                                         bqkv, rwT, x, norm1_w, h_bf);

    // 1) fused QKV   (24 x 32 = 768 blocks)
    mgemm<0><<<dim3(QKV_M / BT, S / BT), 256, 0, stream>>>(
        h_bf, wqkvT, bqkv, qkv, nullptr, nullptr, D, QKV_M, nullptr, nullptr,
        nullptr);

    // 2) attention -> bf16 ao
    attn_kernel<<<dim3(S / QB, NKV), 256, 0, stream>>>(qkv, sink, ao_bf);

    // 3) x1 = x + ao@wo + bo   (16 x 32 = 512 blocks)
    mgemm<1><<<dim3(D / BT, S / BT), 256, 0, stream>>>(
        ao_bf, woT, bo, x1, nullptr, x, D, D, nullptr, nullptr, nullptr);

    // 4) fused rmsnorm2 + router; pre-init out = x1
    rms_router_kernel<<<NTOK, 256, 0, stream>>>(x1, norm2_w, h2b, rwT,
                                                router_b, probs, top_i, top_g,
                                                out);

    // 5) finalize + scatter (LDS cursors)
    finalize_scatter_kernel<<<1, 256, 0, stream>>>(
        probs, top_i, top_g, offs, tok_idx, tok_gate, slot_of,
        out + (size_t)S * D);

    // 6) MoE GEMM1 (gather fused: A rows = h2b[tok_idx[slot]])
    mgemm<2><<<dim3(HDIM / BT, NSLOT / BT, E_), 256, 0, stream>>>(
        h2b, w1T, b1, nullptr, hmid, nullptr, D, HDIM, offs, nullptr, tok_idx);

    // 7) MoE GEMM2 (combine fused: atomic out[tok] += gate*(val+bias))
    mgemm<3><<<dim3(D / BT, NSLOT / BT, E_), 256, 0, stream>>>(
        hmid, w2T, b2, out, nullptr, nullptr, HDIM, D, offs, tok_gate, tok_idx);
}